// Round 12
// baseline (251.826 us; speedup 1.0000x reference)
//
#include <hip/hip_runtime.h>

// ---------------------------------------------------------------------------
// ROIAwareGCN: 3x GCNConv + mean-pool + MLP.
// R1..R28: see journal. Survivors: MFMA split-bf16 GEMMs, fp8 e4m3 gather
// tables, 128-row-bucket binning + single-pass k_csr (R19/R23/R28 packed),
// aggemm fusion (R22/R23), agg64+poolmlp tail (R23).
// Lessons: R20 no un-staged scatters; R22 no contended global atomics;
// R24/R26/R27 bin->csr is at floor (R28: packing neutral -> not
// traffic-bound); R25 aggs TLP-saturated -> VMEM ISSUE COUNT is the lever
// (R18's mechanism).
// R29: gathers widened to 16B/lane (uint4). aggemm128: 8 lanes/row x 8
// edge-groups = 2 col + 2 gathers per 16 edges (was 4+4). agg64: 4 lanes/row
// x 16 groups = 1+1 (was 2+2). Same cache-line traffic, half the VMEM
// instructions; +1 shfl reduce stage.
// ---------------------------------------------------------------------------

typedef __bf16 bf16x8 __attribute__((ext_vector_type(8)));
typedef float f32x4 __attribute__((ext_vector_type(4)));
typedef float f32x2 __attribute__((ext_vector_type(2)));

__device__ __forceinline__ unsigned char f32_to_fp8(float v) {
    return (unsigned char)(__builtin_amdgcn_cvt_pk_fp8_f32(v, 0.f, 0, false) & 0xff);
}
__device__ __forceinline__ void acc8_fp8(float* a, unsigned ux, unsigned uy) {
    f32x2 v;
    v = __builtin_amdgcn_cvt_pk_f32_fp8(ux, false); a[0] += v.x; a[1] += v.y;
    v = __builtin_amdgcn_cvt_pk_f32_fp8(ux, true);  a[2] += v.x; a[3] += v.y;
    v = __builtin_amdgcn_cvt_pk_f32_fp8(uy, false); a[4] += v.x; a[5] += v.y;
    v = __builtin_amdgcn_cvt_pk_f32_fp8(uy, true);  a[6] += v.x; a[7] += v.y;
}
__device__ __forceinline__ void acc16_fp8(float* a, uint4 u) {
    acc8_fp8(a, u.x, u.y);
    acc8_fp8(a + 8, u.z, u.w);
}

union BF2 {
    __bf16 h[2];
    unsigned u;
};

#define PAD(c) (((c) + 15) & ~15)
#define BCAP 64
#define ECHUNK 4096
#define ECAP 4096     // LDS edge cache per bucket (T mean ~1535, ~65 sigma margin)
#define BUCKCAP 4096  // col slots per bucket (sum pad16(deg) mean ~2253)

// ---------------- W pre-pack into MFMA B-fragment layout ----------------
__device__ __forceinline__ void wpack_block(const float* __restrict__ W,
                                            __bf16* __restrict__ hi,
                                            __bf16* __restrict__ lo, int N, int b, int l) {
    int t = b >> 2, c = b & 3;
    int k0 = c * 32 + (l >> 4) * 8;
    int ncol = t * 16 + (l & 15);
    size_t base = ((size_t)b * 64 + l) * 8;
#pragma unroll
    for (int j = 0; j < 8; j++) {
        float v = W[(size_t)(k0 + j) * N + ncol];
        __bf16 h = (__bf16)v;
        hi[base + j] = h;
        lo[base + j] = (__bf16)(v - (float)h);
    }
}

// ---- k_bin: block-private edge binning (packed 4B) + gstart + wpack ----
__global__ __launch_bounds__(1024) void k_bin(const int* __restrict__ src,
                                              const int* __restrict__ dst,
                                              unsigned int* __restrict__ binbuf,
                                              int* __restrict__ bcnt,
                                              const int* __restrict__ batch,
                                              int* __restrict__ gstart,
                                              const float* __restrict__ W1,
                                              const float* __restrict__ W2,
                                              const float* __restrict__ W3,
                                              __bf16* __restrict__ Wp1h, __bf16* __restrict__ Wp1l,
                                              __bf16* __restrict__ Wp2h, __bf16* __restrict__ Wp2l,
                                              __bf16* __restrict__ Wp3h, __bf16* __restrict__ Wp3l,
                                              int E, int EC, int nbuck, int n, int G) {
    int b = blockIdx.x;
    int tid = threadIdx.x;
    if (b < EC) {
        __shared__ int lcur[512];
        for (int i = tid; i < nbuck; i += 1024) lcur[i] = 0;
        __syncthreads();
        int e0 = b * ECHUNK;
        int cntE = E - e0;
        if (cntE > ECHUNK) cntE = ECHUNK;
#pragma unroll
        for (int k = 0; k < 4; k++) {
            int idx = tid + k * 1024;
            if (idx < cntE) {
                int s = src[e0 + idx];
                int d = dst[e0 + idx];
                int bk = d >> 7;
                int slot = atomicAdd(&lcur[bk], 1);
                if (slot < BCAP) {
                    // pack: src (16b, n<65536) | row-in-bucket (7b) << 16
                    binbuf[((size_t)b * nbuck + bk) * BCAP + slot] =
                        (unsigned)s | ((unsigned)(d & 127) << 16);
                }
            }
        }
        __syncthreads();
        for (int bk = tid; bk < nbuck; bk += 1024) {
            int c = lcur[bk];
            bcnt[b * nbuck + bk] = (c < BCAP) ? c : BCAP;
        }
        return;
    }
    if (b == EC) {
        int g = tid;
        if (g <= G) {
            int lo = 0, hi = n;
            while (lo < hi) {
                int mid = (lo + hi) >> 1;
                if (batch[mid] < g) lo = mid + 1; else hi = mid;
            }
            gstart[g] = lo;
        }
        return;
    }
    int b64 = (b - EC - 1) * 16 + (tid >> 6);  // 0..79
    int l = tid & 63;
    if (b64 < 32) wpack_block(W1, Wp1h, Wp1l, 128, b64, l);
    else if (b64 < 64) wpack_block(W2, Wp2h, Wp2l, 128, b64 - 32, l);
    else if (b64 < 80) wpack_block(W3, Wp3h, Wp3l, 64, b64 - 64, l);
}

// ---- k_csr: single-pass per-bucket CSR build (deg + dinv + rowspan + col) ----
__global__ __launch_bounds__(1024) void k_csr(const unsigned int* __restrict__ binbuf,
                                              const int* __restrict__ bcnt,
                                              float* __restrict__ dinv,
                                              int2* __restrict__ rowspan,
                                              int* __restrict__ col,
                                              unsigned int* __restrict__ tzA,
                                              unsigned int* __restrict__ tzB,
                                              unsigned int* __restrict__ tz64,
                                              int n, int EC, int nbuck) {
    __shared__ int lcnt[160];
    __shared__ int lpre[161];
    __shared__ int deg[128];
    __shared__ int lloc[129];
    __shared__ int lfill[128];
    __shared__ unsigned int sedge[ECAP];  // packed src|row<<16
    __shared__ int cols_s[BUCKCAP];
    int b = blockIdx.x;
    int tid = threadIdx.x;
    int lane = tid & 63;
    int wid = tid >> 6;
    int r0 = b << 7;
    int r1 = r0 + 128;
    if (r1 > n) r1 = n;
    int nrows = r1 - r0;
    if (b == 0) {  // zero row n of the three fp8 gather targets
        if (tid < 32) tzA[(size_t)n * 32 + tid] = 0u;
        else if (tid < 64) tzB[(size_t)n * 32 + (tid - 32)] = 0u;
        else if (tid < 80) tz64[(size_t)n * 16 + (tid - 64)] = 0u;
    }
    for (int c = tid; c < EC; c += 1024) lcnt[c] = bcnt[c * nbuck + b];
    if (tid < 128) deg[tid] = 0;
    __syncthreads();
    if (wid == 0) {  // scan chunk counts -> lpre
        int carry = 0;
        for (int bb = 0; bb < EC; bb += 64) {
            int idx = bb + lane;
            int val = (idx < EC) ? lcnt[idx] : 0;
            int sc = val;
#pragma unroll
            for (int d = 1; d < 64; d <<= 1) {
                int o = __shfl_up(sc, d);
                if (lane >= d) sc += o;
            }
            int grp = __shfl(sc, 63);
            if (idx < EC) lpre[idx] = sc - val + carry;
            carry += grp;
        }
        if (lane == 0) lpre[EC] = carry;
    }
    __syncthreads();
    int T = lpre[EC];
    // pass 1: one binbuf read; cache packed edges in LDS; count degrees
    for (int i = tid; i < T; i += 1024) {
        int lo = 0, hi = EC;
        while (lo < hi) {
            int mid = (lo + hi) >> 1;
            if (lpre[mid + 1] <= i) lo = mid + 1; else hi = mid;
        }
        int j = i - lpre[lo];
        unsigned pk = binbuf[((size_t)lo * nbuck + b) * BCAP + j];
        atomicAdd(&deg[pk >> 16], 1);
        if (i < ECAP) sedge[i] = pk;
    }
    __syncthreads();
    if (wid == 0) {  // scan padded row degs -> local offsets
        int carry = 0;
#pragma unroll
        for (int bb = 0; bb < 128; bb += 64) {
            int idx = bb + lane;
            int val = (idx < nrows) ? PAD(deg[idx]) : 0;
            int sc = val;
#pragma unroll
            for (int d = 1; d < 64; d <<= 1) {
                int o = __shfl_up(sc, d);
                if (lane >= d) sc += o;
            }
            int grp = __shfl(sc, 63);
            lloc[idx] = sc - val + carry;
            carry += grp;
        }
        if (lane == 0) lloc[128] = carry;
    }
    __syncthreads();
    int base = b * BUCKCAP;
    int tot = lloc[128];
    if (tot > BUCKCAP) tot = BUCKCAP;  // unreachable guard
    if (tid < nrows) {
        int d = deg[tid];
        lfill[tid] = lloc[tid];
        dinv[r0 + tid] = rsqrtf((float)(d + 1));
        int st = base + lloc[tid];
        int2 sp = {st, st + d};
        rowspan[r0 + tid] = sp;
    }
    for (int i = tid; i < tot; i += 1024) cols_s[i] = n;  // pads -> zero row
    __syncthreads();
    int Tc = (T < ECAP) ? T : ECAP;
    for (int i = tid; i < Tc; i += 1024) {
        unsigned pk = sedge[i];
        int pos = atomicAdd(&lfill[pk >> 16], 1);
        if (pos < BUCKCAP) cols_s[pos] = (int)(pk & 0xffffu);
    }
    // overflow path (statistically unreachable): re-read binbuf for i >= ECAP
    for (int i = ECAP + tid; i < T; i += 1024) {
        int lo = 0, hi = EC;
        while (lo < hi) {
            int mid = (lo + hi) >> 1;
            if (lpre[mid + 1] <= i) lo = mid + 1; else hi = mid;
        }
        int j = i - lpre[lo];
        unsigned pk = binbuf[((size_t)lo * nbuck + b) * BCAP + j];
        int pos = atomicAdd(&lfill[pk >> 16], 1);
        if (pos < BUCKCAP) cols_s[pos] = (int)(pk & 0xffffu);
    }
    __syncthreads();
    for (int i = tid; i < tot; i += 1024) col[base + i] = cols_s[i];
}

// ---- gemm1: fp32 A, hi/lo split, 3 mfma per K-chunk; *dinv; fp8 out ----
__global__ __launch_bounds__(256) void k_gemm1(const float* __restrict__ A,
                                               const __bf16* __restrict__ Wp_hi,
                                               const __bf16* __restrict__ Wp_lo,
                                               const float* __restrict__ dinv,
                                               unsigned char* __restrict__ Cf8, int n) {
    constexpr int NT = 8;
    constexpr int N = NT * 16;
    int wave = (int)((blockIdx.x * 256u + threadIdx.x) >> 6);
    int lane = threadIdx.x & 63;
    int row0 = wave * 16;
    if (row0 >= n) return;
    int m = lane & 15;
    int q = lane >> 4;
    int row = row0 + m;
    if (row >= n) row = n - 1;
    const float* ap = A + (size_t)row * 128 + q * 8;
    bf16x8 ahi[4], alo[4];
#pragma unroll
    for (int c = 0; c < 4; c++) {
        float4 v0 = *(const float4*)(ap + c * 32);
        float4 v1 = *(const float4*)(ap + c * 32 + 4);
        float vv[8] = {v0.x, v0.y, v0.z, v0.w, v1.x, v1.y, v1.z, v1.w};
#pragma unroll
        for (int j = 0; j < 8; j++) {
            __bf16 h = (__bf16)vv[j];
            ahi[c][j] = h;
            alo[c][j] = (__bf16)(vv[j] - (float)h);
        }
    }
    float dscale[4];
#pragma unroll
    for (int r = 0; r < 4; r++) {
        int rr = row0 + q * 4 + r;
        dscale[r] = dinv[rr < n ? rr : (n - 1)];
    }
#pragma unroll
    for (int t = 0; t < NT; t++) {
        f32x4 acc = {0.f, 0.f, 0.f, 0.f};
#pragma unroll
        for (int c = 0; c < 4; c++) {
            size_t off = ((size_t)(t * 4 + c) * 64 + lane) * 8;
            bf16x8 bh = *(const bf16x8*)(Wp_hi + off);
            bf16x8 bl = *(const bf16x8*)(Wp_lo + off);
            acc = __builtin_amdgcn_mfma_f32_16x16x32_bf16(ahi[c], bh, acc, 0, 0, 0);
            acc = __builtin_amdgcn_mfma_f32_16x16x32_bf16(alo[c], bh, acc, 0, 0, 0);
            acc = __builtin_amdgcn_mfma_f32_16x16x32_bf16(ahi[c], bl, acc, 0, 0, 0);
        }
        int colx = t * 16 + m;
#pragma unroll
        for (int r = 0; r < 4; r++) {
            int orow = row0 + q * 4 + r;
            if (orow < n) Cf8[(size_t)orow * N + colx] = f32_to_fp8(acc[r] * dscale[r]);
        }
    }
}

// ---- k_aggemm: fused agg(128ch, uint4 gathers) -> LDS A-tile -> MFMA gemm ----
// Phase A: wave v aggregates rows v*4..v*4+3; 8 lanes/row (16 ch each) x
// 8 edge-groups: 2 col loads + 2 gathers per 16 edges.
template <int NT>
__global__ __launch_bounds__(256) void k_aggemm(const unsigned char* __restrict__ t8,
                                                const int2* __restrict__ rowspan,
                                                const int* __restrict__ col,
                                                const float* __restrict__ dinv,
                                                const float* __restrict__ bias,
                                                const __bf16* __restrict__ Wp_hi,
                                                const __bf16* __restrict__ Wp_lo,
                                                unsigned char* __restrict__ Cf8, int n) {
    constexpr int N = NT * 16;
    __shared__ __align__(16) __bf16 As[16][136];
    int row0 = blockIdx.x * 16;
    int tid = threadIdx.x;
    int lane = tid & 63;
    int v = tid >> 6;
    const uint4* t8v = (const uint4*)t8;  // row = 8 uint4
    int cl = lane & 7;    // channel quarter: ch 16*cl .. 16*cl+15
    int g = lane >> 3;    // edge sub-group 0..7
    float4 bq0 = *(const float4*)(bias + cl * 16);
    float4 bq1 = *(const float4*)(bias + cl * 16 + 4);
    float4 bq2 = *(const float4*)(bias + cl * 16 + 8);
    float4 bq3 = *(const float4*)(bias + cl * 16 + 12);
    float bv[16] = {bq0.x, bq0.y, bq0.z, bq0.w, bq1.x, bq1.y, bq1.z, bq1.w,
                    bq2.x, bq2.y, bq2.z, bq2.w, bq3.x, bq3.y, bq3.z, bq3.w};
#pragma unroll 1
    for (int r = 0; r < 4; r++) {
        int lr = v * 4 + r;
        int w = row0 + lr;
        if (w < n) {
            float acc[16];
#pragma unroll
            for (int j = 0; j < 16; j++) acc[j] = 0.f;
            int2 rs = rowspan[w];
            int p = rs.x;
            int pend = p + ((rs.y - rs.x + 15) & ~15);
            for (; p < pend; p += 16) {
                int c0 = col[p + g];
                int c1 = col[p + 8 + g];
                uint4 u0 = t8v[((size_t)c0 << 3) + cl];
                uint4 u1 = t8v[((size_t)c1 << 3) + cl];
                acc16_fp8(acc, u0);
                acc16_fp8(acc, u1);
            }
            // combine the 8 edge sub-groups (bits 3,4,5 of lane); cl preserved
#pragma unroll
            for (int j = 0; j < 16; j++) {
                acc[j] += __shfl_xor(acc[j], 8);
                acc[j] += __shfl_xor(acc[j], 16);
                acc[j] += __shfl_xor(acc[j], 32);
            }
            {   // self term (broadcast load, consistent in every lane)
                uint4 us = t8v[((size_t)w << 3) + cl];
                float s16[16];
#pragma unroll
                for (int j = 0; j < 16; j++) s16[j] = 0.f;
                acc16_fp8(s16, us);
#pragma unroll
                for (int j = 0; j < 16; j++) acc[j] += s16[j];
            }
            float di = dinv[w];
            BF2 o[8];
#pragma unroll
            for (int j = 0; j < 8; j++) {
                o[j].h[0] = (__bf16)fmaxf(di * acc[2 * j] + bv[2 * j], 0.f);
                o[j].h[1] = (__bf16)fmaxf(di * acc[2 * j + 1] + bv[2 * j + 1], 0.f);
            }
            if (lane < 8) {
                uint4 st0 = {o[0].u, o[1].u, o[2].u, o[3].u};
                uint4 st1 = {o[4].u, o[5].u, o[6].u, o[7].u};
                *(uint4*)&As[lr][cl * 16] = st0;
                *(uint4*)&As[lr][cl * 16 + 8] = st1;
            }
        } else if (lane < 8) {
            uint4 z = {0u, 0u, 0u, 0u};
            *(uint4*)&As[lr][cl * 16] = z;
            *(uint4*)&As[lr][cl * 16 + 8] = z;
        }
    }
    __syncthreads();
    // ---- phase B: MFMA transform of the 16-row tile ----
    int m = lane & 15;
    int q = lane >> 4;
    bf16x8 a[4];
#pragma unroll
    for (int c = 0; c < 4; c++) a[c] = *(const bf16x8*)&As[m][q * 8 + c * 32];
    float dscale[4];
#pragma unroll
    for (int r = 0; r < 4; r++) {
        int rr = row0 + q * 4 + r;
        dscale[r] = dinv[rr < n ? rr : (n - 1)];
    }
    constexpr int TPW = NT / 4;
#pragma unroll
    for (int tt = 0; tt < TPW; tt++) {
        int t = v * TPW + tt;
        f32x4 acc = {0.f, 0.f, 0.f, 0.f};
#pragma unroll
        for (int c = 0; c < 4; c++) {
            size_t off = ((size_t)(t * 4 + c) * 64 + lane) * 8;
            bf16x8 bh = *(const bf16x8*)(Wp_hi + off);
            bf16x8 bl = *(const bf16x8*)(Wp_lo + off);
            acc = __builtin_amdgcn_mfma_f32_16x16x32_bf16(a[c], bh, acc, 0, 0, 0);
            acc = __builtin_amdgcn_mfma_f32_16x16x32_bf16(a[c], bl, acc, 0, 0, 0);
        }
        int colx = t * 16 + m;
#pragma unroll
        for (int r = 0; r < 4; r++) {
            int orow = row0 + q * 4 + r;
            if (orow < n) Cf8[(size_t)orow * N + colx] = f32_to_fp8(acc[r] * dscale[r]);
        }
    }
}

// ---- k_agg64: 64-ch gather-sum (uint4), relu -> bf16 h3 ----
// 4 lanes/row (16 ch each) x 16 edge-groups: 1 col load + 1 gather / 16 edges.
__global__ __launch_bounds__(256) void k_agg64(const unsigned char* __restrict__ t8,
                                               const int2* __restrict__ rowspan,
                                               const int* __restrict__ col,
                                               const float* __restrict__ dinv,
                                               const float* __restrict__ bias,
                                               __bf16* __restrict__ out, int n) {
    int w = (int)((blockIdx.x * 256u + threadIdx.x) >> 6);
    int lane = threadIdx.x & 63;
    if (w >= n) return;
    const uint4* t8v = (const uint4*)t8;  // row = 4 uint4
    int cl = lane & 3;    // channel quarter: ch 16*cl .. 16*cl+15
    int g = lane >> 2;    // edge sub-group 0..15
    float acc[16];
#pragma unroll
    for (int j = 0; j < 16; j++) acc[j] = 0.f;
    int2 rs = rowspan[w];
    int p = rs.x;
    int pend = p + ((rs.y - rs.x + 15) & ~15);
    for (; p < pend; p += 16) {
        int c = col[p + g];
        uint4 u = t8v[((size_t)c << 2) + cl];
        acc16_fp8(acc, u);
    }
    // combine the 16 edge sub-groups (bits 2..5 of lane); cl preserved
#pragma unroll
    for (int j = 0; j < 16; j++) {
        acc[j] += __shfl_xor(acc[j], 4);
        acc[j] += __shfl_xor(acc[j], 8);
        acc[j] += __shfl_xor(acc[j], 16);
        acc[j] += __shfl_xor(acc[j], 32);
    }
    {   // self term
        uint4 us = t8v[((size_t)w << 2) + cl];
        float s16[16];
#pragma unroll
        for (int j = 0; j < 16; j++) s16[j] = 0.f;
        acc16_fp8(s16, us);
#pragma unroll
        for (int j = 0; j < 16; j++) acc[j] += s16[j];
    }
    float di = dinv[w];
    float4 bq0 = *(const float4*)(bias + cl * 16);
    float4 bq1 = *(const float4*)(bias + cl * 16 + 4);
    float4 bq2 = *(const float4*)(bias + cl * 16 + 8);
    float4 bq3 = *(const float4*)(bias + cl * 16 + 12);
    float bv[16] = {bq0.x, bq0.y, bq0.z, bq0.w, bq1.x, bq1.y, bq1.z, bq1.w,
                    bq2.x, bq2.y, bq2.z, bq2.w, bq3.x, bq3.y, bq3.z, bq3.w};
    BF2 o[8];
#pragma unroll
    for (int j = 0; j < 8; j++) {
        o[j].h[0] = (__bf16)fmaxf(di * acc[2 * j] + bv[2 * j], 0.f);
        o[j].h[1] = (__bf16)fmaxf(di * acc[2 * j + 1] + bv[2 * j + 1], 0.f);
    }
    if (lane < 4) {
        uint4 st0 = {o[0].u, o[1].u, o[2].u, o[3].u};
        uint4 st1 = {o[4].u, o[5].u, o[6].u, o[7].u};
        unsigned* op = (unsigned*)out + (size_t)w * 32 + cl * 8;
        *(uint4*)op = st0;
        *(uint4*)(op + 4) = st1;
    }
}

// ---------------- fused mean-pool + MLP head ----------------
__global__ __launch_bounds__(256) void k_poolmlp(const unsigned short* __restrict__ h,
                                                 const int* __restrict__ gstart,
                                                 const float* __restrict__ demo,
                                                 const float* __restrict__ Wf1,
                                                 const float* __restrict__ bf1,
                                                 const float* __restrict__ Wf2,
                                                 const float* __restrict__ bf2,
                                                 const float* __restrict__ Wf3,
                                                 const float* __restrict__ bf3,
                                                 float* __restrict__ out, int G) {
    int g = blockIdx.x;
    int tid = threadIdx.x;
    int lane = tid & 63;
    int wv = tid >> 6;
    int s = gstart[g], e = gstart[g + 1];
    const unsigned* hu = (const unsigned*)h;
    int cg = lane & 15;   // ch 4*cg .. 4*cg+3
    int sub = lane >> 4;  // row offset 0..3
    float acc[4] = {0.f, 0.f, 0.f, 0.f};
    for (int i = s + wv * 4 + sub; i < e; i += 16) {
        uint2 v = *(const uint2*)(hu + ((size_t)i << 5) + cg * 2);
        acc[0] += __uint_as_float(v.x << 16);
        acc[1] += __uint_as_float(v.x & 0xffff0000u);
        acc[2] += __uint_as_float(v.y << 16);
        acc[3] += __uint_as_float(v.y & 0xffff0000u);
    }
#pragma unroll
    for (int j = 0; j < 4; j++) {
        acc[j] += __shfl_xor(acc[j], 16);
        acc[j] += __shfl_xor(acc[j], 32);
    }
    __shared__ float red[4][64];
    __shared__ float zin[72];
    __shared__ float z1[64];
    __shared__ float z2[32];
    if (sub == 0) {
#pragma unroll
        for (int j = 0; j < 4; j++) red[wv][cg * 4 + j] = acc[j];
    }
    if (tid >= 64 && tid < 72) zin[tid] = demo[g * 8 + (tid - 64)];
    __syncthreads();
    if (tid < 64) {
        float v = red[0][tid] + red[1][tid] + red[2][tid] + red[3][tid];
        zin[tid] = v / fmaxf((float)(e - s), 1.0f);
    }
    __syncthreads();
    if (tid < 64) {
        float a = bf1[tid];
        for (int k = 0; k < 72; k++) a += zin[k] * Wf1[k * 64 + tid];
        z1[tid] = fmaxf(a, 0.f);
    }
    __syncthreads();
    if (tid < 32) {
        float a2 = bf2[tid];
        for (int k = 0; k < 64; k++) a2 += z1[k] * Wf2[k * 32 + tid];
        z2[tid] = fmaxf(a2, 0.f);
    }
    __syncthreads();
    if (tid < 2) {
        float a3 = bf3[tid];
        for (int k = 0; k < 32; k++) a3 += z2[k] * Wf3[k * 2 + tid];
        out[g * 2 + tid] = a3;
    }
}

extern "C" void kernel_launch(void* const* d_in, const int* in_sizes, int n_in,
                              void* d_out, int out_size, void* d_ws, size_t ws_size,
                              hipStream_t stream) {
    const float* x    = (const float*)d_in[0];
    const int*   ei   = (const int*)d_in[1];
    const int*   batch= (const int*)d_in[2];
    const float* demo = (const float*)d_in[3];
    const float* W1   = (const float*)d_in[4];
    const float* b1   = (const float*)d_in[5];
    const float* W2   = (const float*)d_in[6];
    const float* b2   = (const float*)d_in[7];
    const float* W3   = (const float*)d_in[8];
    const float* b3   = (const float*)d_in[9];
    const float* Wf1  = (const float*)d_in[10];
    const float* bf1  = (const float*)d_in[11];
    const float* Wf2  = (const float*)d_in[12];
    const float* bf2  = (const float*)d_in[13];
    const float* Wf3  = (const float*)d_in[14];
    const float* bf3  = (const float*)d_in[15];
    float* out = (float*)d_out;

    const int n = in_sizes[0] / 128;  // 50000 (src ids fit in 16 bits)
    const int E = in_sizes[1] / 2;    // 600000
    const int G = in_sizes[3] / 8;    // 100
    const int EC = (E + ECHUNK - 1) / ECHUNK;    // edge chunks (147)
    const int nbuck = (n + 127) / 128;           // row buckets (391)

    char* ws = (char*)d_ws;
    auto alloc = [&](size_t bytes) {
        char* p = ws;
        ws += (bytes + 255) & ~(size_t)255;
        return p;
    };
    float*  dinv    = (float*)alloc((size_t)n * 4);
    int2*   rowspan = (int2*)alloc((size_t)n * 8);
    int*    col     = (int*)alloc((size_t)nbuck * BUCKCAP * 4 + 256);
    unsigned int* binbuf = (unsigned int*)alloc((size_t)EC * nbuck * BCAP * 4);
    int*    bcnt    = (int*)alloc((size_t)EC * nbuck * 4);
    unsigned char* tbf  = (unsigned char*)alloc((size_t)(n + 1) * 128);  // fp8 ts layer 1
    unsigned char* tbf2 = (unsigned char*)alloc((size_t)(n + 1) * 128);  // fp8 ts layer 2
    unsigned char* t3bf = (unsigned char*)alloc((size_t)(n + 1) * 64);   // fp8 ts layer 3
    __bf16* h3      = (__bf16*)alloc((size_t)n * 64 * 2);                // agg3 out (bf16)
    __bf16* Wp1h    = (__bf16*)alloc(128 * 128 * 2);
    __bf16* Wp1l    = (__bf16*)alloc(128 * 128 * 2);
    __bf16* Wp2h    = (__bf16*)alloc(128 * 128 * 2);
    __bf16* Wp2l    = (__bf16*)alloc(128 * 128 * 2);
    __bf16* Wp3h    = (__bf16*)alloc(128 * 64 * 2);
    __bf16* Wp3l    = (__bf16*)alloc(128 * 64 * 2);
    int*    gstart  = (int*)alloc((size_t)(G + 1) * 4);

    const int* srcv = ei;
    const int* dstv = ei + E;

    int waves = (n + 15) / 16;               // 3125 row-tiles
    int gemm_blocks = (waves + 3) / 4;       // 782 (gemm1: 4 waves/block)
    int fuse_blocks = waves;                 // 3125 (aggemm: 1 tile/block)
    int agg_blocks = (int)(((size_t)n * 64 + 255) / 256);

    // binning (packed 4B) + gstart + wpack
    k_bin<<<EC + 1 + 5, 1024, 0, stream>>>(srcv, dstv, binbuf, bcnt, batch, gstart,
                                           W1, W2, W3, Wp1h, Wp1l, Wp2h, Wp2l,
                                           Wp3h, Wp3l, E, EC, nbuck, n, G);
    // single-pass CSR build: deg + dinv + rowspan + col (+ zero rows of ts)
    k_csr<<<nbuck, 1024, 0, stream>>>(binbuf, bcnt, dinv, rowspan, col,
                                      (unsigned int*)tbf, (unsigned int*)tbf2,
                                      (unsigned int*)t3bf, n, EC, nbuck);
    // Layer 1 transform (fp32 A, split-bf16)
    k_gemm1<<<gemm_blocks, 256, 0, stream>>>(x, Wp1h, Wp1l, dinv, tbf, n);
    // Layer 1 agg + Layer 2 transform (fused via LDS A-tile, uint4 gathers)
    k_aggemm<8><<<fuse_blocks, 256, 0, stream>>>(tbf, rowspan, col, dinv, b1,
                                                 Wp2h, Wp2l, tbf2, n);
    // Layer 2 agg + Layer 3 transform
    k_aggemm<4><<<fuse_blocks, 256, 0, stream>>>(tbf2, rowspan, col, dinv, b2,
                                                 Wp3h, Wp3l, t3bf, n);
    // Layer 3 agg -> h3 (bf16)
    k_agg64<<<agg_blocks, 256, 0, stream>>>(t3bf, rowspan, col, dinv, b3, h3, n);
    // mean-pool + MLP head
    k_poolmlp<<<G, 256, 0, stream>>>((const unsigned short*)h3, gstart, demo,
                                     Wf1, bf1, Wf2, bf2, Wf3, bf3, out, G);
}

// Round 13
// 215.890 us; speedup vs baseline: 1.1665x; 1.1665x over previous
//
#include <hip/hip_runtime.h>

// ---------------------------------------------------------------------------
// ROIAwareGCN: 3x GCNConv + mean-pool + MLP.
// R1..R29: see journal. FINAL CONFIG = R28 (216.7us, reproducing R23's 216.9).
// Survivors: MFMA split-bf16 GEMMs (dinv in epilogue), fp8 e4m3 gather
// tables (R17), 8B/lane sub-wave-group gathers (R18: the measured optimum --
// R29's 16B/lane regressed +35us via VALU/reg pressure), 16-edge branchless
// loops (R21), 128-row-bucket binning + single-pass k_csr (R19/R23), packed
// 4B binbuf (R28), aggemm fusion (R22/R23), agg64+poolmlp tail (R23).
// Dead ends (all measured): R20 un-staged scatter (+60); R22 contended
// atomic pool (+280); R24 counting-sort csr (+30); R25 ILP pairing (+6);
// R26 64-row buckets (+5); R27 atomics-in-bin bundle (+25); R29 uint4 (+35).
// R29's counters show aggemm latency-bound, no pipe saturated: practical
// floor for this scatter-gather pipeline.
// ---------------------------------------------------------------------------

typedef __bf16 bf16x8 __attribute__((ext_vector_type(8)));
typedef float f32x4 __attribute__((ext_vector_type(4)));
typedef float f32x2 __attribute__((ext_vector_type(2)));

__device__ __forceinline__ unsigned char f32_to_fp8(float v) {
    return (unsigned char)(__builtin_amdgcn_cvt_pk_fp8_f32(v, 0.f, 0, false) & 0xff);
}
__device__ __forceinline__ void acc8_fp8(float* a, uint2 u) {
    f32x2 v;
    v = __builtin_amdgcn_cvt_pk_f32_fp8(u.x, false); a[0] += v.x; a[1] += v.y;
    v = __builtin_amdgcn_cvt_pk_f32_fp8(u.x, true);  a[2] += v.x; a[3] += v.y;
    v = __builtin_amdgcn_cvt_pk_f32_fp8(u.y, false); a[4] += v.x; a[5] += v.y;
    v = __builtin_amdgcn_cvt_pk_f32_fp8(u.y, true);  a[6] += v.x; a[7] += v.y;
}

union BF2 {
    __bf16 h[2];
    unsigned u;
};

#define PAD(c) (((c) + 15) & ~15)
#define BCAP 64
#define ECHUNK 4096
#define ECAP 4096     // LDS edge cache per bucket (T mean ~1535, ~65 sigma margin)
#define BUCKCAP 4096  // col slots per bucket (sum pad16(deg) mean ~2253)

// ---------------- W pre-pack into MFMA B-fragment layout ----------------
__device__ __forceinline__ void wpack_block(const float* __restrict__ W,
                                            __bf16* __restrict__ hi,
                                            __bf16* __restrict__ lo, int N, int b, int l) {
    int t = b >> 2, c = b & 3;
    int k0 = c * 32 + (l >> 4) * 8;
    int ncol = t * 16 + (l & 15);
    size_t base = ((size_t)b * 64 + l) * 8;
#pragma unroll
    for (int j = 0; j < 8; j++) {
        float v = W[(size_t)(k0 + j) * N + ncol];
        __bf16 h = (__bf16)v;
        hi[base + j] = h;
        lo[base + j] = (__bf16)(v - (float)h);
    }
}

// ---- k_bin: block-private edge binning (packed 4B) + gstart + wpack ----
__global__ __launch_bounds__(1024) void k_bin(const int* __restrict__ src,
                                              const int* __restrict__ dst,
                                              unsigned int* __restrict__ binbuf,
                                              int* __restrict__ bcnt,
                                              const int* __restrict__ batch,
                                              int* __restrict__ gstart,
                                              const float* __restrict__ W1,
                                              const float* __restrict__ W2,
                                              const float* __restrict__ W3,
                                              __bf16* __restrict__ Wp1h, __bf16* __restrict__ Wp1l,
                                              __bf16* __restrict__ Wp2h, __bf16* __restrict__ Wp2l,
                                              __bf16* __restrict__ Wp3h, __bf16* __restrict__ Wp3l,
                                              int E, int EC, int nbuck, int n, int G) {
    int b = blockIdx.x;
    int tid = threadIdx.x;
    if (b < EC) {
        __shared__ int lcur[512];
        for (int i = tid; i < nbuck; i += 1024) lcur[i] = 0;
        __syncthreads();
        int e0 = b * ECHUNK;
        int cntE = E - e0;
        if (cntE > ECHUNK) cntE = ECHUNK;
#pragma unroll
        for (int k = 0; k < 4; k++) {
            int idx = tid + k * 1024;
            if (idx < cntE) {
                int s = src[e0 + idx];
                int d = dst[e0 + idx];
                int bk = d >> 7;
                int slot = atomicAdd(&lcur[bk], 1);
                if (slot < BCAP) {
                    // pack: src (16b, n<65536) | row-in-bucket (7b) << 16
                    binbuf[((size_t)b * nbuck + bk) * BCAP + slot] =
                        (unsigned)s | ((unsigned)(d & 127) << 16);
                }
            }
        }
        __syncthreads();
        for (int bk = tid; bk < nbuck; bk += 1024) {
            int c = lcur[bk];
            bcnt[b * nbuck + bk] = (c < BCAP) ? c : BCAP;
        }
        return;
    }
    if (b == EC) {
        int g = tid;
        if (g <= G) {
            int lo = 0, hi = n;
            while (lo < hi) {
                int mid = (lo + hi) >> 1;
                if (batch[mid] < g) lo = mid + 1; else hi = mid;
            }
            gstart[g] = lo;
        }
        return;
    }
    int b64 = (b - EC - 1) * 16 + (tid >> 6);  // 0..79
    int l = tid & 63;
    if (b64 < 32) wpack_block(W1, Wp1h, Wp1l, 128, b64, l);
    else if (b64 < 64) wpack_block(W2, Wp2h, Wp2l, 128, b64 - 32, l);
    else if (b64 < 80) wpack_block(W3, Wp3h, Wp3l, 64, b64 - 64, l);
}

// ---- k_csr: single-pass per-bucket CSR build (deg + dinv + rowspan + col) ----
__global__ __launch_bounds__(1024) void k_csr(const unsigned int* __restrict__ binbuf,
                                              const int* __restrict__ bcnt,
                                              float* __restrict__ dinv,
                                              int2* __restrict__ rowspan,
                                              int* __restrict__ col,
                                              unsigned int* __restrict__ tzA,
                                              unsigned int* __restrict__ tzB,
                                              unsigned int* __restrict__ tz64,
                                              int n, int EC, int nbuck) {
    __shared__ int lcnt[160];
    __shared__ int lpre[161];
    __shared__ int deg[128];
    __shared__ int lloc[129];
    __shared__ int lfill[128];
    __shared__ unsigned int sedge[ECAP];  // packed src|row<<16
    __shared__ int cols_s[BUCKCAP];
    int b = blockIdx.x;
    int tid = threadIdx.x;
    int lane = tid & 63;
    int wid = tid >> 6;
    int r0 = b << 7;
    int r1 = r0 + 128;
    if (r1 > n) r1 = n;
    int nrows = r1 - r0;
    if (b == 0) {  // zero row n of the three fp8 gather targets
        if (tid < 32) tzA[(size_t)n * 32 + tid] = 0u;
        else if (tid < 64) tzB[(size_t)n * 32 + (tid - 32)] = 0u;
        else if (tid < 80) tz64[(size_t)n * 16 + (tid - 64)] = 0u;
    }
    for (int c = tid; c < EC; c += 1024) lcnt[c] = bcnt[c * nbuck + b];
    if (tid < 128) deg[tid] = 0;
    __syncthreads();
    if (wid == 0) {  // scan chunk counts -> lpre
        int carry = 0;
        for (int bb = 0; bb < EC; bb += 64) {
            int idx = bb + lane;
            int val = (idx < EC) ? lcnt[idx] : 0;
            int sc = val;
#pragma unroll
            for (int d = 1; d < 64; d <<= 1) {
                int o = __shfl_up(sc, d);
                if (lane >= d) sc += o;
            }
            int grp = __shfl(sc, 63);
            if (idx < EC) lpre[idx] = sc - val + carry;
            carry += grp;
        }
        if (lane == 0) lpre[EC] = carry;
    }
    __syncthreads();
    int T = lpre[EC];
    // pass 1: one binbuf read; cache packed edges in LDS; count degrees
    // (all binned entries are valid: dst of a bucket's edge is in-bucket)
    for (int i = tid; i < T; i += 1024) {
        int lo = 0, hi = EC;
        while (lo < hi) {
            int mid = (lo + hi) >> 1;
            if (lpre[mid + 1] <= i) lo = mid + 1; else hi = mid;
        }
        int j = i - lpre[lo];
        unsigned pk = binbuf[((size_t)lo * nbuck + b) * BCAP + j];
        atomicAdd(&deg[pk >> 16], 1);
        if (i < ECAP) sedge[i] = pk;
    }
    __syncthreads();
    if (wid == 0) {  // scan padded row degs -> local offsets
        int carry = 0;
#pragma unroll
        for (int bb = 0; bb < 128; bb += 64) {
            int idx = bb + lane;
            int val = (idx < nrows) ? PAD(deg[idx]) : 0;
            int sc = val;
#pragma unroll
            for (int d = 1; d < 64; d <<= 1) {
                int o = __shfl_up(sc, d);
                if (lane >= d) sc += o;
            }
            int grp = __shfl(sc, 63);
            lloc[idx] = sc - val + carry;
            carry += grp;
        }
        if (lane == 0) lloc[128] = carry;
    }
    __syncthreads();
    int base = b * BUCKCAP;
    int tot = lloc[128];
    if (tot > BUCKCAP) tot = BUCKCAP;  // unreachable guard
    if (tid < nrows) {
        int d = deg[tid];
        lfill[tid] = lloc[tid];
        dinv[r0 + tid] = rsqrtf((float)(d + 1));
        int st = base + lloc[tid];
        int2 sp = {st, st + d};
        rowspan[r0 + tid] = sp;
    }
    for (int i = tid; i < tot; i += 1024) cols_s[i] = n;  // pads -> zero row
    __syncthreads();
    int Tc = (T < ECAP) ? T : ECAP;
    for (int i = tid; i < Tc; i += 1024) {
        unsigned pk = sedge[i];
        int pos = atomicAdd(&lfill[pk >> 16], 1);
        if (pos < BUCKCAP) cols_s[pos] = (int)(pk & 0xffffu);
    }
    // overflow path (statistically unreachable): re-read binbuf for i >= ECAP
    for (int i = ECAP + tid; i < T; i += 1024) {
        int lo = 0, hi = EC;
        while (lo < hi) {
            int mid = (lo + hi) >> 1;
            if (lpre[mid + 1] <= i) lo = mid + 1; else hi = mid;
        }
        int j = i - lpre[lo];
        unsigned pk = binbuf[((size_t)lo * nbuck + b) * BCAP + j];
        int pos = atomicAdd(&lfill[pk >> 16], 1);
        if (pos < BUCKCAP) cols_s[pos] = (int)(pk & 0xffffu);
    }
    __syncthreads();
    for (int i = tid; i < tot; i += 1024) col[base + i] = cols_s[i];
}

// ---- gemm1: fp32 A, hi/lo split, 3 mfma per K-chunk; *dinv; fp8 out ----
__global__ __launch_bounds__(256) void k_gemm1(const float* __restrict__ A,
                                               const __bf16* __restrict__ Wp_hi,
                                               const __bf16* __restrict__ Wp_lo,
                                               const float* __restrict__ dinv,
                                               unsigned char* __restrict__ Cf8, int n) {
    constexpr int NT = 8;
    constexpr int N = NT * 16;
    int wave = (int)((blockIdx.x * 256u + threadIdx.x) >> 6);
    int lane = threadIdx.x & 63;
    int row0 = wave * 16;
    if (row0 >= n) return;
    int m = lane & 15;
    int q = lane >> 4;
    int row = row0 + m;
    if (row >= n) row = n - 1;
    const float* ap = A + (size_t)row * 128 + q * 8;
    bf16x8 ahi[4], alo[4];
#pragma unroll
    for (int c = 0; c < 4; c++) {
        float4 v0 = *(const float4*)(ap + c * 32);
        float4 v1 = *(const float4*)(ap + c * 32 + 4);
        float vv[8] = {v0.x, v0.y, v0.z, v0.w, v1.x, v1.y, v1.z, v1.w};
#pragma unroll
        for (int j = 0; j < 8; j++) {
            __bf16 h = (__bf16)vv[j];
            ahi[c][j] = h;
            alo[c][j] = (__bf16)(vv[j] - (float)h);
        }
    }
    float dscale[4];
#pragma unroll
    for (int r = 0; r < 4; r++) {
        int rr = row0 + q * 4 + r;
        dscale[r] = dinv[rr < n ? rr : (n - 1)];
    }
#pragma unroll
    for (int t = 0; t < NT; t++) {
        f32x4 acc = {0.f, 0.f, 0.f, 0.f};
#pragma unroll
        for (int c = 0; c < 4; c++) {
            size_t off = ((size_t)(t * 4 + c) * 64 + lane) * 8;
            bf16x8 bh = *(const bf16x8*)(Wp_hi + off);
            bf16x8 bl = *(const bf16x8*)(Wp_lo + off);
            acc = __builtin_amdgcn_mfma_f32_16x16x32_bf16(ahi[c], bh, acc, 0, 0, 0);
            acc = __builtin_amdgcn_mfma_f32_16x16x32_bf16(alo[c], bh, acc, 0, 0, 0);
            acc = __builtin_amdgcn_mfma_f32_16x16x32_bf16(ahi[c], bl, acc, 0, 0, 0);
        }
        int colx = t * 16 + m;
#pragma unroll
        for (int r = 0; r < 4; r++) {
            int orow = row0 + q * 4 + r;
            if (orow < n) Cf8[(size_t)orow * N + colx] = f32_to_fp8(acc[r] * dscale[r]);
        }
    }
}

// ---- k_aggemm: fused agg(128ch fp8 gather) -> LDS A-tile -> MFMA gemm ----
template <int NT>
__global__ __launch_bounds__(256) void k_aggemm(const unsigned char* __restrict__ t8,
                                                const int2* __restrict__ rowspan,
                                                const int* __restrict__ col,
                                                const float* __restrict__ dinv,
                                                const float* __restrict__ bias,
                                                const __bf16* __restrict__ Wp_hi,
                                                const __bf16* __restrict__ Wp_lo,
                                                unsigned char* __restrict__ Cf8, int n) {
    constexpr int N = NT * 16;
    __shared__ __bf16 As[16][136];
    int row0 = blockIdx.x * 16;
    int tid = threadIdx.x;
    int lane = tid & 63;
    int v = tid >> 6;
    const uint2* t8v = (const uint2*)t8;
    int cg = lane & 15;   // channel group: ch 8*cg .. 8*cg+7
    int g = lane >> 4;    // edge sub-group 0..3
    float4 bb0 = *(const float4*)(bias + cg * 8);
    float4 bb1 = *(const float4*)(bias + cg * 8 + 4);
    float bv[8] = {bb0.x, bb0.y, bb0.z, bb0.w, bb1.x, bb1.y, bb1.z, bb1.w};
#pragma unroll 1
    for (int r = 0; r < 4; r++) {
        int lr = v * 4 + r;
        int w = row0 + lr;
        if (w < n) {
            float acc[8] = {0.f, 0.f, 0.f, 0.f, 0.f, 0.f, 0.f, 0.f};
            int2 rs = rowspan[w];
            int p = rs.x;
            int pend = p + ((rs.y - rs.x + 15) & ~15);
            for (; p < pend; p += 16) {
                int c0 = col[p + g];
                int c1 = col[p + 4 + g];
                int c2 = col[p + 8 + g];
                int c3 = col[p + 12 + g];
                uint2 u0 = t8v[((size_t)c0 << 4) + cg];
                uint2 u1 = t8v[((size_t)c1 << 4) + cg];
                uint2 u2 = t8v[((size_t)c2 << 4) + cg];
                uint2 u3 = t8v[((size_t)c3 << 4) + cg];
                acc8_fp8(acc, u0);
                acc8_fp8(acc, u1);
                acc8_fp8(acc, u2);
                acc8_fp8(acc, u3);
            }
#pragma unroll
            for (int j = 0; j < 8; j++) {
                acc[j] += __shfl_xor(acc[j], 16);
                acc[j] += __shfl_xor(acc[j], 32);
            }
            {   // self term
                uint2 us = t8v[((size_t)w << 4) + cg];
                float s8[8] = {0.f, 0.f, 0.f, 0.f, 0.f, 0.f, 0.f, 0.f};
                acc8_fp8(s8, us);
#pragma unroll
                for (int j = 0; j < 8; j++) acc[j] += s8[j];
            }
            float di = dinv[w];
            BF2 o[4];
#pragma unroll
            for (int j = 0; j < 4; j++) {
                o[j].h[0] = (__bf16)fmaxf(di * acc[2 * j] + bv[2 * j], 0.f);
                o[j].h[1] = (__bf16)fmaxf(di * acc[2 * j + 1] + bv[2 * j + 1], 0.f);
            }
            if (lane < 16) {
                uint4 st = {o[0].u, o[1].u, o[2].u, o[3].u};
                *(uint4*)&As[lr][cg * 8] = st;
            }
        } else if (lane < 16) {
            uint4 z = {0u, 0u, 0u, 0u};
            *(uint4*)&As[lr][cg * 8] = z;
        }
    }
    __syncthreads();
    // ---- phase B: MFMA transform of the 16-row tile ----
    int m = lane & 15;
    int q = lane >> 4;
    bf16x8 a[4];
#pragma unroll
    for (int c = 0; c < 4; c++) a[c] = *(const bf16x8*)&As[m][q * 8 + c * 32];
    float dscale[4];
#pragma unroll
    for (int r = 0; r < 4; r++) {
        int rr = row0 + q * 4 + r;
        dscale[r] = dinv[rr < n ? rr : (n - 1)];
    }
    constexpr int TPW = NT / 4;
#pragma unroll
    for (int tt = 0; tt < TPW; tt++) {
        int t = v * TPW + tt;
        f32x4 acc = {0.f, 0.f, 0.f, 0.f};
#pragma unroll
        for (int c = 0; c < 4; c++) {
            size_t off = ((size_t)(t * 4 + c) * 64 + lane) * 8;
            bf16x8 bh = *(const bf16x8*)(Wp_hi + off);
            bf16x8 bl = *(const bf16x8*)(Wp_lo + off);
            acc = __builtin_amdgcn_mfma_f32_16x16x32_bf16(a[c], bh, acc, 0, 0, 0);
            acc = __builtin_amdgcn_mfma_f32_16x16x32_bf16(a[c], bl, acc, 0, 0, 0);
        }
        int colx = t * 16 + m;
#pragma unroll
        for (int r = 0; r < 4; r++) {
            int orow = row0 + q * 4 + r;
            if (orow < n) Cf8[(size_t)orow * N + colx] = f32_to_fp8(acc[r] * dscale[r]);
        }
    }
}

// ---- k_agg64: 64-ch gather-sum + relu -> bf16 h3 (16 edges/iter) ----
__global__ __launch_bounds__(256) void k_agg64(const unsigned char* __restrict__ t8,
                                               const int2* __restrict__ rowspan,
                                               const int* __restrict__ col,
                                               const float* __restrict__ dinv,
                                               const float* __restrict__ bias,
                                               __bf16* __restrict__ out, int n) {
    int w = (int)((blockIdx.x * 256u + threadIdx.x) >> 6);
    int lane = threadIdx.x & 63;
    if (w >= n) return;
    const uint2* t8v = (const uint2*)t8;
    int cg = lane & 7;    // channel group: ch 8*cg .. 8*cg+7
    int g = lane >> 3;    // edge sub-group 0..7
    float acc[8] = {0.f, 0.f, 0.f, 0.f, 0.f, 0.f, 0.f, 0.f};
    int2 rs = rowspan[w];
    int p = rs.x;
    int pend = p + ((rs.y - rs.x + 15) & ~15);
    for (; p < pend; p += 16) {
        int c0 = col[p + g];
        int c1 = col[p + 8 + g];
        uint2 u0 = t8v[((size_t)c0 << 3) + cg];
        uint2 u1 = t8v[((size_t)c1 << 3) + cg];
        acc8_fp8(acc, u0);
        acc8_fp8(acc, u1);
    }
#pragma unroll
    for (int j = 0; j < 8; j++) {
        acc[j] += __shfl_xor(acc[j], 8);
        acc[j] += __shfl_xor(acc[j], 16);
        acc[j] += __shfl_xor(acc[j], 32);
    }
    {   // self term
        uint2 us = t8v[((size_t)w << 3) + cg];
        float s8[8] = {0.f, 0.f, 0.f, 0.f, 0.f, 0.f, 0.f, 0.f};
        acc8_fp8(s8, us);
#pragma unroll
        for (int j = 0; j < 8; j++) acc[j] += s8[j];
    }
    float di = dinv[w];
    float4 bb0 = *(const float4*)(bias + cg * 8);
    float4 bb1 = *(const float4*)(bias + cg * 8 + 4);
    float bv[8] = {bb0.x, bb0.y, bb0.z, bb0.w, bb1.x, bb1.y, bb1.z, bb1.w};
    BF2 o[4];
#pragma unroll
    for (int j = 0; j < 4; j++) {
        o[j].h[0] = (__bf16)fmaxf(di * acc[2 * j] + bv[2 * j], 0.f);
        o[j].h[1] = (__bf16)fmaxf(di * acc[2 * j + 1] + bv[2 * j + 1], 0.f);
    }
    if (lane < 8) {
        uint4 st = {o[0].u, o[1].u, o[2].u, o[3].u};
        *(uint4*)((unsigned int*)out + (size_t)w * 32 + cg * 4) = st;
    }
}

// ---------------- fused mean-pool + MLP head ----------------
__global__ __launch_bounds__(256) void k_poolmlp(const unsigned short* __restrict__ h,
                                                 const int* __restrict__ gstart,
                                                 const float* __restrict__ demo,
                                                 const float* __restrict__ Wf1,
                                                 const float* __restrict__ bf1,
                                                 const float* __restrict__ Wf2,
                                                 const float* __restrict__ bf2,
                                                 const float* __restrict__ Wf3,
                                                 const float* __restrict__ bf3,
                                                 float* __restrict__ out, int G) {
    int g = blockIdx.x;
    int tid = threadIdx.x;
    int lane = tid & 63;
    int wv = tid >> 6;
    int s = gstart[g], e = gstart[g + 1];
    const unsigned* hu = (const unsigned*)h;
    int cg = lane & 15;   // ch 4*cg .. 4*cg+3
    int sub = lane >> 4;  // row offset 0..3
    float acc[4] = {0.f, 0.f, 0.f, 0.f};
    for (int i = s + wv * 4 + sub; i < e; i += 16) {
        uint2 v = *(const uint2*)(hu + ((size_t)i << 5) + cg * 2);
        acc[0] += __uint_as_float(v.x << 16);
        acc[1] += __uint_as_float(v.x & 0xffff0000u);
        acc[2] += __uint_as_float(v.y << 16);
        acc[3] += __uint_as_float(v.y & 0xffff0000u);
    }
#pragma unroll
    for (int j = 0; j < 4; j++) {
        acc[j] += __shfl_xor(acc[j], 16);
        acc[j] += __shfl_xor(acc[j], 32);
    }
    __shared__ float red[4][64];
    __shared__ float zin[72];
    __shared__ float z1[64];
    __shared__ float z2[32];
    if (sub == 0) {
#pragma unroll
        for (int j = 0; j < 4; j++) red[wv][cg * 4 + j] = acc[j];
    }
    if (tid >= 64 && tid < 72) zin[tid] = demo[g * 8 + (tid - 64)];
    __syncthreads();
    if (tid < 64) {
        float v = red[0][tid] + red[1][tid] + red[2][tid] + red[3][tid];
        zin[tid] = v / fmaxf((float)(e - s), 1.0f);
    }
    __syncthreads();
    if (tid < 64) {
        float a = bf1[tid];
        for (int k = 0; k < 72; k++) a += zin[k] * Wf1[k * 64 + tid];
        z1[tid] = fmaxf(a, 0.f);
    }
    __syncthreads();
    if (tid < 32) {
        float a2 = bf2[tid];
        for (int k = 0; k < 64; k++) a2 += z1[k] * Wf2[k * 32 + tid];
        z2[tid] = fmaxf(a2, 0.f);
    }
    __syncthreads();
    if (tid < 2) {
        float a3 = bf3[tid];
        for (int k = 0; k < 32; k++) a3 += z2[k] * Wf3[k * 2 + tid];
        out[g * 2 + tid] = a3;
    }
}

extern "C" void kernel_launch(void* const* d_in, const int* in_sizes, int n_in,
                              void* d_out, int out_size, void* d_ws, size_t ws_size,
                              hipStream_t stream) {
    const float* x    = (const float*)d_in[0];
    const int*   ei   = (const int*)d_in[1];
    const int*   batch= (const int*)d_in[2];
    const float* demo = (const float*)d_in[3];
    const float* W1   = (const float*)d_in[4];
    const float* b1   = (const float*)d_in[5];
    const float* W2   = (const float*)d_in[6];
    const float* b2   = (const float*)d_in[7];
    const float* W3   = (const float*)d_in[8];
    const float* b3   = (const float*)d_in[9];
    const float* Wf1  = (const float*)d_in[10];
    const float* bf1  = (const float*)d_in[11];
    const float* Wf2  = (const float*)d_in[12];
    const float* bf2  = (const float*)d_in[13];
    const float* Wf3  = (const float*)d_in[14];
    const float* bf3  = (const float*)d_in[15];
    float* out = (float*)d_out;

    const int n = in_sizes[0] / 128;  // 50000 (src ids fit in 16 bits)
    const int E = in_sizes[1] / 2;    // 600000
    const int G = in_sizes[3] / 8;    // 100
    const int EC = (E + ECHUNK - 1) / ECHUNK;    // edge chunks (147)
    const int nbuck = (n + 127) / 128;           // row buckets (391)

    char* ws = (char*)d_ws;
    auto alloc = [&](size_t bytes) {
        char* p = ws;
        ws += (bytes + 255) & ~(size_t)255;
        return p;
    };
    float*  dinv    = (float*)alloc((size_t)n * 4);
    int2*   rowspan = (int2*)alloc((size_t)n * 8);
    int*    col     = (int*)alloc((size_t)nbuck * BUCKCAP * 4 + 256);
    unsigned int* binbuf = (unsigned int*)alloc((size_t)EC * nbuck * BCAP * 4);
    int*    bcnt    = (int*)alloc((size_t)EC * nbuck * 4);
    unsigned char* tbf  = (unsigned char*)alloc((size_t)(n + 1) * 128);  // fp8 ts layer 1
    unsigned char* tbf2 = (unsigned char*)alloc((size_t)(n + 1) * 128);  // fp8 ts layer 2
    unsigned char* t3bf = (unsigned char*)alloc((size_t)(n + 1) * 64);   // fp8 ts layer 3
    __bf16* h3      = (__bf16*)alloc((size_t)n * 64 * 2);                // agg3 out (bf16)
    __bf16* Wp1h    = (__bf16*)alloc(128 * 128 * 2);
    __bf16* Wp1l    = (__bf16*)alloc(128 * 128 * 2);
    __bf16* Wp2h    = (__bf16*)alloc(128 * 128 * 2);
    __bf16* Wp2l    = (__bf16*)alloc(128 * 128 * 2);
    __bf16* Wp3h    = (__bf16*)alloc(128 * 64 * 2);
    __bf16* Wp3l    = (__bf16*)alloc(128 * 64 * 2);
    int*    gstart  = (int*)alloc((size_t)(G + 1) * 4);

    const int* srcv = ei;
    const int* dstv = ei + E;

    int waves = (n + 15) / 16;               // 3125 row-tiles
    int gemm_blocks = (waves + 3) / 4;       // 782 (gemm1: 4 waves/block)
    int fuse_blocks = waves;                 // 3125 (aggemm: 1 tile/block)
    int agg_blocks = (int)(((size_t)n * 64 + 255) / 256);

    // binning (packed 4B) + gstart + wpack
    k_bin<<<EC + 1 + 5, 1024, 0, stream>>>(srcv, dstv, binbuf, bcnt, batch, gstart,
                                           W1, W2, W3, Wp1h, Wp1l, Wp2h, Wp2l,
                                           Wp3h, Wp3l, E, EC, nbuck, n, G);
    // single-pass CSR build: deg + dinv + rowspan + col (+ zero rows of ts)
    k_csr<<<nbuck, 1024, 0, stream>>>(binbuf, bcnt, dinv, rowspan, col,
                                      (unsigned int*)tbf, (unsigned int*)tbf2,
                                      (unsigned int*)t3bf, n, EC, nbuck);
    // Layer 1 transform (fp32 A, split-bf16)
    k_gemm1<<<gemm_blocks, 256, 0, stream>>>(x, Wp1h, Wp1l, dinv, tbf, n);
    // Layer 1 agg + Layer 2 transform (fused via LDS A-tile)
    k_aggemm<8><<<fuse_blocks, 256, 0, stream>>>(tbf, rowspan, col, dinv, b1,
                                                 Wp2h, Wp2l, tbf2, n);
    // Layer 2 agg + Layer 3 transform
    k_aggemm<4><<<fuse_blocks, 256, 0, stream>>>(tbf2, rowspan, col, dinv, b2,
                                                 Wp3h, Wp3l, t3bf, n);
    // Layer 3 agg -> h3 (bf16)
    k_agg64<<<agg_blocks, 256, 0, stream>>>(t3bf, rowspan, col, dinv, b3, h3, n);
    // mean-pool + MLP head
    k_poolmlp<<<G, 256, 0, stream>>>((const unsigned short*)h3, gstart, demo,
                                     Wf1, bf1, Wf2, bf2, Wf3, bf3, out, G);
}